// Round 1
// baseline (4322.812 us; speedup 1.0000x reference)
//
#include <hip/hip_runtime.h>
#include <math.h>

#define BS 256
#define MM 128
#define NN 1024
#define ITERS 100
#define ALPHA 0.1f

// ---------------------------------------------------------------------------
// Transpose A (BS,M,N) -> AT (BS,N,M), coalesced both sides via LDS tile.
// grid (16, 2, BS), block 256
__global__ __launch_bounds__(256) void k_transpose(const float* __restrict__ A,
                                                   float* __restrict__ AT) {
  __shared__ float tile[64][65];
  int nt = blockIdx.x, mt = blockIdx.y, b = blockIdx.z;
  int lane = threadIdx.x & 63;
  int grp  = threadIdx.x >> 6;  // 0..3
  const float* Ab = A + (size_t)b * MM * NN;
  float* ATb = AT + (size_t)b * NN * MM;
  int n0 = nt * 64, m0 = mt * 64;
#pragma unroll
  for (int it = 0; it < 16; ++it) {
    int ml = it * 4 + grp;
    tile[ml][lane] = Ab[(size_t)(m0 + ml) * NN + n0 + lane];
  }
  __syncthreads();
#pragma unroll
  for (int it = 0; it < 16; ++it) {
    int nl = it * 4 + grp;
    ATb[(size_t)(n0 + nl) * MM + m0 + lane] = tile[lane][nl];
  }
}

// ---------------------------------------------------------------------------
// AAT: C[b] = A[b] * A[b]^T  (128x128), one block per batch, 512 threads.
// LDS tile k-major [k][m] stride 129; thread computes 4x8 C-block at strided
// rows i = ig+32*aa, cols j = jg+16*cc (conflict-free LDS reads).
#define AST 129
__global__ __launch_bounds__(512) void k_aat(const float* __restrict__ A,
                                             float* __restrict__ C) {
  __shared__ float As[64 * AST];
  int b = blockIdx.x;
  int tid = threadIdx.x;
  const float* Ab = A + (size_t)b * MM * NN;
  float* Cb = C + (size_t)b * MM * MM;
  int ig = tid >> 4;   // 0..31
  int jg = tid & 15;   // 0..15
  float acc[4][8];
#pragma unroll
  for (int aa = 0; aa < 4; ++aa)
#pragma unroll
    for (int cc = 0; cc < 8; ++cc) acc[aa][cc] = 0.0f;

  for (int t = 0; t < 16; ++t) {
    int k0 = t * 64;
#pragma unroll
    for (int s = 0; s < 4; ++s) {
      int c = tid + s * 512;        // 0..2047
      int m = c >> 4;               // 0..127
      int kk = (c & 15) << 2;       // 0..60
      float4 v = *(const float4*)&Ab[(size_t)m * NN + k0 + kk];
      As[(kk + 0) * AST + m] = v.x;
      As[(kk + 1) * AST + m] = v.y;
      As[(kk + 2) * AST + m] = v.z;
      As[(kk + 3) * AST + m] = v.w;
    }
    __syncthreads();
#pragma unroll 4
    for (int k = 0; k < 64; ++k) {
      float av[4], bv[8];
#pragma unroll
      for (int aa = 0; aa < 4; ++aa) av[aa] = As[k * AST + ig + 32 * aa];
#pragma unroll
      for (int cc = 0; cc < 8; ++cc) bv[cc] = As[k * AST + jg + 16 * cc];
#pragma unroll
      for (int aa = 0; aa < 4; ++aa)
#pragma unroll
        for (int cc = 0; cc < 8; ++cc) acc[aa][cc] += av[aa] * bv[cc];
    }
    __syncthreads();
  }
#pragma unroll
  for (int aa = 0; aa < 4; ++aa)
#pragma unroll
    for (int cc = 0; cc < 8; ++cc)
      Cb[(size_t)(ig + 32 * aa) * MM + jg + 16 * cc] = acc[aa][cc];
}

// ---------------------------------------------------------------------------
// In-place Gauss-Jordan inverse of SPD 128x128 (no pivoting; AAT is SPD,
// cond ~5). One block per batch, 256 threads, 64 KB LDS exactly.
__global__ __launch_bounds__(256) void k_inv(float* __restrict__ G) {
  __shared__ float Msh[MM * MM];
  int b = blockIdx.x;
  int tid = threadIdx.x;
  float* Gb = G + (size_t)b * MM * MM;
#pragma unroll
  for (int s = 0; s < 16; ++s) {
    int idx = (tid + s * 256) * 4;
    *(float4*)&Msh[idx] = *(const float4*)&Gb[idx];
  }
  __syncthreads();
  int j = tid & 127;
  int ibase = (tid >> 7) << 6;
  for (int k = 0; k < MM; ++k) {
    float p = 1.0f / Msh[k * MM + k];
    // scale row k (j != k), col k left untouched for f reads
    if (tid >= 128) {
      int jj = tid - 128;
      if (jj != k) Msh[k * MM + jj] *= p;
    }
    __syncthreads();
    float mkj = (j == k) ? 0.0f : Msh[k * MM + j];
    for (int ii = 0; ii < 64; ++ii) {
      int i = ibase + ii;
      float f = Msh[i * MM + k];  // broadcast, col k still original
      if (i != k && j != k) Msh[i * MM + j] -= f * mkj;
    }
    __syncthreads();
    if (tid < 128) {
      int i = tid;
      float f = Msh[i * MM + k];
      Msh[i * MM + k] = (i == k) ? p : -f * p;
    }
    __syncthreads();
  }
#pragma unroll
  for (int s = 0; s < 16; ++s) {
    int idx = (tid + s * 256) * 4;
    *(float4*)&Gb[idx] = *(const float4*)&Msh[idx];
  }
}

// ---------------------------------------------------------------------------
// Persistent solver: one block per batch, 512 threads (8 waves).
// Fused pass i: corr_i = A^T u_i (butterfly over half-wave), z_{i+1} =
// S(z_i) - corr_i, y_{i+1} = 2 S(z_{i+1}) - z_{i+1}, t_{i+1} += A y_{i+1}
// using the SAME registers holding the A column fragment (one A read/pass).
__global__ __launch_bounds__(512) void k_main(const float* __restrict__ AT,
                                              const float* __restrict__ G,
                                              const float* __restrict__ bvec,
                                              const float* __restrict__ D1,
                                              const float* __restrict__ D2,
                                              float* __restrict__ out) {
  __shared__ __align__(16) float z_sh[NN];
  __shared__ __align__(16) float td_sh[NN];
  __shared__ __align__(16) float di_sh[NN];
  __shared__ __align__(16) float b_sh[MM];
  __shared__ __align__(16) float s_sh[MM];
  __shared__ __align__(16) float u_sh[MM];
  __shared__ __align__(16) float t_red[16][MM];

  int b = blockIdx.x;
  int tid = threadIdx.x;
  const float4* ATv = (const float4*)(AT + (size_t)b * NN * MM);
  const float* Gb = G + (size_t)b * MM * MM;

  // ---- prologue: G rows into registers (32 consecutive floats per thread)
  float g[32];
#pragma unroll
  for (int s = 0; s < 8; ++s) {
    float4 v = *(const float4*)&Gb[32 * tid + 4 * s];
    g[4 * s + 0] = v.x; g[4 * s + 1] = v.y;
    g[4 * s + 2] = v.z; g[4 * s + 3] = v.w;
  }
  if (tid < MM) b_sh[tid] = bvec[(size_t)b * MM + tid];
  for (int c = tid; c < NN; c += 512) {
    float d1 = D1[(size_t)b * NN + c];
    float d2 = D2[(size_t)b * NN + c];
    td_sh[c] = ALPHA * fabsf(d1);
    di_sh[c] = 1.0f / (1.0f + 2.0f * ALPHA * d2 * d2);
    z_sh[c] = 0.0f;
  }
  __syncthreads();
  if (tid < MM) s_sh[tid] = -b_sh[tid];  // s_0 = A*y_0 - b = -b
  __syncthreads();

  int l = tid & 31;                             // lane within half-wave
  int hw = tid >> 5;                            // half-wave id 0..15
  int nbase = ((tid >> 6) << 7) + ((tid >> 5) & 1);  // wave*128 + hw-bit

  for (int it = 0; it < ITERS; ++it) {
    bool last = (it == ITERS - 1);
    // ---- u = G * s  (4 threads per row of G)
    {
      float up = 0.0f;
      int j0 = (tid & 3) * 32;
#pragma unroll
      for (int jj = 0; jj < 32; ++jj) up += g[jj] * s_sh[j0 + jj];
      up += __shfl_xor(up, 1);
      up += __shfl_xor(up, 2);
      if ((tid & 3) == 0) u_sh[tid >> 2] = up;
    }
    __syncthreads();
    float4 uv = *(const float4*)&u_sh[4 * l];  // u[4l..4l+3], fixed this pass
    float t0 = 0.0f, t1 = 0.0f, t2 = 0.0f, t3 = 0.0f;

    for (int s = 0; s < 64; ++s) {
      int n = nbase + 2 * s;  // this half-wave's column
      float4 a = ATv[(size_t)n * 32 + l];  // AT[n][4l..4l+3] (coalesced 1KB/wave)
      float cp = a.x * uv.x + a.y * uv.y + a.z * uv.z + a.w * uv.w;
      cp += __shfl_xor(cp, 16);
      cp += __shfl_xor(cp, 8);
      cp += __shfl_xor(cp, 4);
      cp += __shfl_xor(cp, 2);
      cp += __shfl_xor(cp, 1);  // all 32 lanes now hold corr[n]
      float zn = z_sh[n];
      float td = td_sh[n];
      float di = di_sh[n];
      float xm = zn - td, xp = zn + td;
      float xh = xm > 0.0f ? xm * di : (xp < 0.0f ? xp * di : 0.0f);
      if (!last) {
        float z1 = xh - cp;                    // z_{i+1}
        float xm1 = z1 - td, xp1 = z1 + td;
        float xh1 = xm1 > 0.0f ? xm1 * di : (xp1 < 0.0f ? xp1 * di : 0.0f);
        float y = 2.0f * xh1 - z1;             // y_{i+1}
        if (l == 0) z_sh[n] = z1;
        t0 += a.x * y; t1 += a.y * y; t2 += a.z * y; t3 += a.w * y;
      } else {
        float y = 2.0f * xh - zn;              // y_99 from z_99
        float x = y - cp;                      // x_99
        if (l == 0) z_sh[n] = x;               // stash output in z_sh
      }
    }

    if (!last) {
      float4 tp; tp.x = t0; tp.y = t1; tp.z = t2; tp.w = t3;
      *(float4*)&t_red[hw][4 * l] = tp;
      __syncthreads();
      if (tid < MM) {
        float ssum = -b_sh[tid];
#pragma unroll
        for (int h = 0; h < 16; ++h) ssum += t_red[h][tid];
        s_sh[tid] = ssum;  // s = A*y - b for next pass's u
      }
      __syncthreads();
    }
  }
  __syncthreads();
  float* outb = out + (size_t)b * NN;
  for (int c = tid; c < NN; c += 512) outb[c] = z_sh[c];
}

// ---------------------------------------------------------------------------
extern "C" void kernel_launch(void* const* d_in, const int* in_sizes, int n_in,
                              void* d_out, int out_size, void* d_ws, size_t ws_size,
                              hipStream_t stream) {
  const float* A  = (const float*)d_in[0];  // (BS, M, N)
  const float* bv = (const float*)d_in[1];  // (BS, M)
  const float* D1 = (const float*)d_in[2];  // (BS, N)
  const float* D2 = (const float*)d_in[3];  // (BS, N)
  float* out = (float*)d_out;               // (BS, N)

  float* AT = (float*)d_ws;                          // BS*N*M floats (134 MB)
  float* G  = AT + (size_t)BS * NN * MM;             // BS*M*M floats (16.7 MB)

  k_transpose<<<dim3(16, 2, BS), 256, 0, stream>>>(A, AT);
  k_aat<<<BS, 512, 0, stream>>>(A, G);
  k_inv<<<BS, 256, 0, stream>>>(G);
  k_main<<<BS, 512, 0, stream>>>(AT, G, bv, D1, D2, out);
}

// Round 2
// 3260.716 us; speedup vs baseline: 1.3257x; 1.3257x over previous
//
#include <hip/hip_runtime.h>
#include <math.h>

#define BS 256
#define MM 128
#define NN 1024
#define ITERS 100
#define ALPHA 0.1f

typedef _Float16 half2_t __attribute__((ext_vector_type(2)));

union HU {
  float4 f;
  half2_t h[4];
};

// ---------------------------------------------------------------------------
// AAT: C[b] = A[b] * A[b]^T  (128x128), one block per batch, 512 threads.
// LDS tile k-major [k][m] stride 129. ALSO emits AT in fp16 (the tile is
// already transposed layout), fusing the former k_transpose kernel.
#define AST 129
__global__ __launch_bounds__(512) void k_aat(const float* __restrict__ A,
                                             float* __restrict__ C,
                                             _Float16* __restrict__ ATh) {
  __shared__ float As[64 * AST];
  int b = blockIdx.x;
  int tid = threadIdx.x;
  const float* Ab = A + (size_t)b * MM * NN;
  float* Cb = C + (size_t)b * MM * MM;
  _Float16* ATb = ATh + (size_t)b * NN * MM;
  int ig = tid >> 4;   // 0..31
  int jg = tid & 15;   // 0..15
  float acc[4][8];
#pragma unroll
  for (int aa = 0; aa < 4; ++aa)
#pragma unroll
    for (int cc = 0; cc < 8; ++cc) acc[aa][cc] = 0.0f;

  for (int t = 0; t < 16; ++t) {
    int k0 = t * 64;
#pragma unroll
    for (int s = 0; s < 4; ++s) {
      int c = tid + s * 512;        // 0..2047
      int m = c >> 4;               // 0..127
      int kk = (c & 15) << 2;       // 0..60
      float4 v = *(const float4*)&Ab[(size_t)m * NN + k0 + kk];
      As[(kk + 0) * AST + m] = v.x;
      As[(kk + 1) * AST + m] = v.y;
      As[(kk + 2) * AST + m] = v.z;
      As[(kk + 3) * AST + m] = v.w;
    }
    __syncthreads();
    // emit fp16 AT for this k-slice: AT[k0+kk][m] = As[kk][m]
#pragma unroll
    for (int s = 0; s < 8; ++s) {
      int idx = tid + s * 512;      // 0..4095
      int nl = idx >> 6;            // 0..63
      int mp = idx & 63;            // m-pair index
      half2_t hv;
      hv.x = (_Float16)As[nl * AST + 2 * mp];
      hv.y = (_Float16)As[nl * AST + 2 * mp + 1];
      *(half2_t*)&ATb[(size_t)(k0 + nl) * MM + 2 * mp] = hv;
    }
#pragma unroll 4
    for (int k = 0; k < 64; ++k) {
      float av[4], bv[8];
#pragma unroll
      for (int aa = 0; aa < 4; ++aa) av[aa] = As[k * AST + ig + 32 * aa];
#pragma unroll
      for (int cc = 0; cc < 8; ++cc) bv[cc] = As[k * AST + jg + 16 * cc];
#pragma unroll
      for (int aa = 0; aa < 4; ++aa)
#pragma unroll
        for (int cc = 0; cc < 8; ++cc) acc[aa][cc] += av[aa] * bv[cc];
    }
    __syncthreads();
  }
#pragma unroll
  for (int aa = 0; aa < 4; ++aa)
#pragma unroll
    for (int cc = 0; cc < 8; ++cc)
      Cb[(size_t)(ig + 32 * aa) * MM + jg + 16 * cc] = acc[aa][cc];
}

// ---------------------------------------------------------------------------
// In-place Gauss-Jordan inverse of SPD 128x128 (no pivoting; AAT is SPD).
// One block per batch, 256 threads, 64 KB LDS exactly.
__global__ __launch_bounds__(256) void k_inv(float* __restrict__ G) {
  __shared__ float Msh[MM * MM];
  int b = blockIdx.x;
  int tid = threadIdx.x;
  float* Gb = G + (size_t)b * MM * MM;
#pragma unroll
  for (int s = 0; s < 16; ++s) {
    int idx = (tid + s * 256) * 4;
    *(float4*)&Msh[idx] = *(const float4*)&Gb[idx];
  }
  __syncthreads();
  int j = tid & 127;
  int ibase = (tid >> 7) << 6;
  for (int k = 0; k < MM; ++k) {
    float p = 1.0f / Msh[k * MM + k];
    if (tid >= 128) {
      int jj = tid - 128;
      if (jj != k) Msh[k * MM + jj] *= p;
    }
    __syncthreads();
    float mkj = (j == k) ? 0.0f : Msh[k * MM + j];
    for (int ii = 0; ii < 64; ++ii) {
      int i = ibase + ii;
      float f = Msh[i * MM + k];
      if (i != k && j != k) Msh[i * MM + j] -= f * mkj;
    }
    __syncthreads();
    if (tid < 128) {
      int i = tid;
      float f = Msh[i * MM + k];
      Msh[i * MM + k] = (i == k) ? p : -f * p;
    }
    __syncthreads();
  }
#pragma unroll
  for (int s = 0; s < 16; ++s) {
    int idx = (tid + s * 256) * 4;
    *(float4*)&Gb[idx] = *(const float4*)&Msh[idx];
  }
}

// ---------------------------------------------------------------------------
// Persistent solver: one block per batch, 1024 threads (16 waves -> 50% occ).
// AT is fp16. 16-lane groups own 16 columns each; per column-step: one 16B
// load (8 halves), fp32-accumulated fdot2 with u (fp16), 4-step shfl_xor
// reduce, fused soft-threshold, and A*y accumulation reusing the registers.
// z lives in registers (group-owned columns), not LDS.
__global__ __launch_bounds__(1024, 4) void k_main(
    const _Float16* __restrict__ AT, const float* __restrict__ G,
    const float* __restrict__ bvec, const float* __restrict__ D1,
    const float* __restrict__ D2, float* __restrict__ out) {
  __shared__ float td_sh[NN];
  __shared__ float di_sh[NN];
  __shared__ float b_sh[MM];
  __shared__ float s_sh[MM];
  __shared__ __align__(16) _Float16 u_h[MM];
  __shared__ float t_red[64][132];   // padded: +4 breaks 8-way conflicts
  __shared__ float t_red2[8][MM];

  int b = blockIdx.x;
  int tid = threadIdx.x;
  const _Float16* ATb = AT + (size_t)b * NN * MM;
  const float* Gb = G + (size_t)b * MM * MM;

  // ---- prologue: G into registers, 8 threads per row, 16 elems each
  int sub = tid & 7, r = tid >> 3;
  float g[16];
#pragma unroll
  for (int s = 0; s < 4; ++s) {
    float4 v = *(const float4*)&Gb[(size_t)r * MM + 16 * sub + 4 * s];
    g[4 * s + 0] = v.x; g[4 * s + 1] = v.y;
    g[4 * s + 2] = v.z; g[4 * s + 3] = v.w;
  }
  {
    float d1 = D1[(size_t)b * NN + tid];
    float d2 = D2[(size_t)b * NN + tid];
    td_sh[tid] = ALPHA * fabsf(d1);
    di_sh[tid] = 1.0f / (1.0f + 2.0f * ALPHA * d2 * d2);
  }
  if (tid < MM) {
    float bb = bvec[(size_t)b * MM + tid];
    b_sh[tid] = bb;
    s_sh[tid] = -bb;   // s_0 = A*y_0 - b = -b
  }
  __syncthreads();

  int l16 = tid & 15;            // lane in 16-group
  int grp = tid >> 4;            // 0..63
  int g4 = grp & 3;              // group within wave
  int w = tid >> 6;              // wave 0..15
  int mbase = 8 * l16;           // this lane's m-chunk (8 m's)
  float zreg[16];
#pragma unroll
  for (int s = 0; s < 16; ++s) zreg[s] = 0.0f;

  for (int it = 0; it < ITERS; ++it) {
    bool last = (it == ITERS - 1);
    // ---- u = G * s  (8 threads per row, fp16 result for fdot2)
    {
      float up = 0.0f;
      int j0 = 16 * sub;
#pragma unroll
      for (int jj = 0; jj < 16; ++jj) up += g[jj] * s_sh[j0 + jj];
      up += __shfl_xor(up, 1);
      up += __shfl_xor(up, 2);
      up += __shfl_xor(up, 4);
      if (sub == 0) u_h[r] = (_Float16)up;
    }
    __syncthreads();
    HU uu;
    uu.f = *(const float4*)&u_h[mbase];
    float t0 = 0, t1 = 0, t2 = 0, t3 = 0, t4 = 0, t5 = 0, t6 = 0, t7 = 0;

#pragma unroll
    for (int s = 0; s < 16; ++s) {
      int n = w * 64 + s * 4 + g4;   // wave's 4 loads are contiguous 1KB
      HU av;
      av.f = *(const float4*)&ATb[(size_t)n * MM + mbase];
      float cp = 0.0f;
#if defined(__has_builtin) && __has_builtin(__builtin_amdgcn_fdot2)
      cp = __builtin_amdgcn_fdot2(av.h[0], uu.h[0], cp, false);
      cp = __builtin_amdgcn_fdot2(av.h[1], uu.h[1], cp, false);
      cp = __builtin_amdgcn_fdot2(av.h[2], uu.h[2], cp, false);
      cp = __builtin_amdgcn_fdot2(av.h[3], uu.h[3], cp, false);
#else
#pragma unroll
      for (int k = 0; k < 4; ++k)
        cp += (float)av.h[k].x * (float)uu.h[k].x +
              (float)av.h[k].y * (float)uu.h[k].y;
#endif
      cp += __shfl_xor(cp, 1);
      cp += __shfl_xor(cp, 2);
      cp += __shfl_xor(cp, 4);
      cp += __shfl_xor(cp, 8);   // all 16 lanes hold corr[n]
      float zn = zreg[s];
      float td = td_sh[n];
      float di = di_sh[n];
      float xm = zn - td, xp = zn + td;
      float xh = xm > 0.0f ? xm * di : (xp < 0.0f ? xp * di : 0.0f);
      if (!last) {
        float z1 = xh - cp;                     // z_{i+1}
        float xm1 = z1 - td, xp1 = z1 + td;
        float xh1 = xm1 > 0.0f ? xm1 * di : (xp1 < 0.0f ? xp1 * di : 0.0f);
        float y = 2.0f * xh1 - z1;              // y_{i+1}
        zreg[s] = z1;
        t0 += (float)av.h[0].x * y; t1 += (float)av.h[0].y * y;
        t2 += (float)av.h[1].x * y; t3 += (float)av.h[1].y * y;
        t4 += (float)av.h[2].x * y; t5 += (float)av.h[2].y * y;
        t6 += (float)av.h[3].x * y; t7 += (float)av.h[3].y * y;
      } else {
        float y = 2.0f * xh - zn;               // y_99 from z_99
        zreg[s] = y - cp;                       // x_99 (output)
      }
    }

    if (!last) {
      float4 ta; ta.x = t0; ta.y = t1; ta.z = t2; ta.w = t3;
      float4 tb; tb.x = t4; tb.y = t5; tb.z = t6; tb.w = t7;
      *(float4*)&t_red[grp][mbase] = ta;
      *(float4*)&t_red[grp][mbase + 4] = tb;
      __syncthreads();
      {
        int p = tid >> 7;        // 0..7
        int m = tid & 127;
        float a2 = 0.0f;
#pragma unroll
        for (int h = 0; h < 8; ++h) a2 += t_red[8 * p + h][m];
        t_red2[p][m] = a2;
      }
      __syncthreads();
      if (tid < MM) {
        float ssum = -b_sh[tid];
#pragma unroll
        for (int p = 0; p < 8; ++p) ssum += t_red2[p][tid];
        s_sh[tid] = ssum;        // s = A*y - b for next pass's u
      }
      __syncthreads();
    }
  }

  if (l16 == 0) {
    float* outb = out + (size_t)b * NN;
#pragma unroll
    for (int s = 0; s < 16; ++s) outb[w * 64 + s * 4 + g4] = zreg[s];
  }
}

// ---------------------------------------------------------------------------
extern "C" void kernel_launch(void* const* d_in, const int* in_sizes, int n_in,
                              void* d_out, int out_size, void* d_ws, size_t ws_size,
                              hipStream_t stream) {
  const float* A  = (const float*)d_in[0];  // (BS, M, N)
  const float* bv = (const float*)d_in[1];  // (BS, M)
  const float* D1 = (const float*)d_in[2];  // (BS, N)
  const float* D2 = (const float*)d_in[3];  // (BS, N)
  float* out = (float*)d_out;               // (BS, N)

  _Float16* ATh = (_Float16*)d_ws;                              // 67 MB
  float* G = (float*)((char*)d_ws + (size_t)BS * NN * MM * 2);  // 16.7 MB

  k_aat<<<BS, 512, 0, stream>>>(A, G, ATh);
  k_inv<<<BS, 256, 0, stream>>>(G);
  k_main<<<BS, 1024, 0, stream>>>(ATh, G, bv, D1, D2, out);
}

// Round 3
// 2716.302 us; speedup vs baseline: 1.5914x; 1.2004x over previous
//
#include <hip/hip_runtime.h>
#include <math.h>

#define BS 256
#define MM 128
#define NN 1024
#define ITERS 100
#define ALPHA 0.1f

typedef _Float16 half2_t __attribute__((ext_vector_type(2)));

union HU {
  float4 f;
  half2_t h[4];
};

// ---------------------------------------------------------------------------
// AAT: C[b] = A[b] * A[b]^T  (128x128), one block per batch, 512 threads.
// LDS tile k-major [k][m] stride 129. ALSO emits AT in fp16 (the tile is
// already transposed layout), fusing the former k_transpose kernel.
#define AST 129
__global__ __launch_bounds__(512) void k_aat(const float* __restrict__ A,
                                             float* __restrict__ C,
                                             _Float16* __restrict__ ATh) {
  __shared__ float As[64 * AST];
  int b = blockIdx.x;
  int tid = threadIdx.x;
  const float* Ab = A + (size_t)b * MM * NN;
  float* Cb = C + (size_t)b * MM * MM;
  _Float16* ATb = ATh + (size_t)b * NN * MM;
  int ig = tid >> 4;   // 0..31
  int jg = tid & 15;   // 0..15
  float acc[4][8];
#pragma unroll
  for (int aa = 0; aa < 4; ++aa)
#pragma unroll
    for (int cc = 0; cc < 8; ++cc) acc[aa][cc] = 0.0f;

  for (int t = 0; t < 16; ++t) {
    int k0 = t * 64;
#pragma unroll
    for (int s = 0; s < 4; ++s) {
      int c = tid + s * 512;        // 0..2047
      int m = c >> 4;               // 0..127
      int kk = (c & 15) << 2;       // 0..60
      float4 v = *(const float4*)&Ab[(size_t)m * NN + k0 + kk];
      As[(kk + 0) * AST + m] = v.x;
      As[(kk + 1) * AST + m] = v.y;
      As[(kk + 2) * AST + m] = v.z;
      As[(kk + 3) * AST + m] = v.w;
    }
    __syncthreads();
    // emit fp16 AT for this k-slice: AT[k0+kk][m] = As[kk][m]
#pragma unroll
    for (int s = 0; s < 8; ++s) {
      int idx = tid + s * 512;      // 0..4095
      int nl = idx >> 6;            // 0..63
      int mp = idx & 63;            // m-pair index
      half2_t hv;
      hv.x = (_Float16)As[nl * AST + 2 * mp];
      hv.y = (_Float16)As[nl * AST + 2 * mp + 1];
      *(half2_t*)&ATb[(size_t)(k0 + nl) * MM + 2 * mp] = hv;
    }
#pragma unroll 4
    for (int k = 0; k < 64; ++k) {
      float av[4], bv[8];
#pragma unroll
      for (int aa = 0; aa < 4; ++aa) av[aa] = As[k * AST + ig + 32 * aa];
#pragma unroll
      for (int cc = 0; cc < 8; ++cc) bv[cc] = As[k * AST + jg + 16 * cc];
#pragma unroll
      for (int aa = 0; aa < 4; ++aa)
#pragma unroll
        for (int cc = 0; cc < 8; ++cc) acc[aa][cc] += av[aa] * bv[cc];
    }
    __syncthreads();
  }
#pragma unroll
  for (int aa = 0; aa < 4; ++aa)
#pragma unroll
    for (int cc = 0; cc < 8; ++cc)
      Cb[(size_t)(ig + 32 * aa) * MM + jg + 16 * cc] = acc[aa][cc];
}

// ---------------------------------------------------------------------------
// In-place Gauss-Jordan inverse of SPD 128x128 (no pivoting; AAT is SPD).
// One block per batch, 256 threads, 64 KB LDS exactly.
__global__ __launch_bounds__(256) void k_inv(float* __restrict__ G) {
  __shared__ float Msh[MM * MM];
  int b = blockIdx.x;
  int tid = threadIdx.x;
  float* Gb = G + (size_t)b * MM * MM;
#pragma unroll
  for (int s = 0; s < 16; ++s) {
    int idx = (tid + s * 256) * 4;
    *(float4*)&Msh[idx] = *(const float4*)&Gb[idx];
  }
  __syncthreads();
  int j = tid & 127;
  int ibase = (tid >> 7) << 6;
  for (int k = 0; k < MM; ++k) {
    float p = 1.0f / Msh[k * MM + k];
    if (tid >= 128) {
      int jj = tid - 128;
      if (jj != k) Msh[k * MM + jj] *= p;
    }
    __syncthreads();
    float mkj = (j == k) ? 0.0f : Msh[k * MM + j];
    for (int ii = 0; ii < 64; ++ii) {
      int i = ibase + ii;
      float f = Msh[i * MM + k];
      if (i != k && j != k) Msh[i * MM + j] -= f * mkj;
    }
    __syncthreads();
    if (tid < 128) {
      int i = tid;
      float f = Msh[i * MM + k];
      Msh[i * MM + k] = (i == k) ? p : -f * p;
    }
    __syncthreads();
  }
#pragma unroll
  for (int s = 0; s < 16; ++s) {
    int idx = (tid + s * 256) * 4;
    *(float4*)&Gb[idx] = *(const float4*)&Msh[idx];
  }
}

// ---------------------------------------------------------------------------
// Persistent solver: one block per batch, 1024 threads (16 waves).
// Hybrid data placement: columns 512..1023 live in LDS (131 KB, loaded once);
// columns 0..511 stream from global (4.2 MB/XCD -> L2-resident).
// Each 16-lane group owns 16 columns (8 global + 8 LDS); global loads issue
// first and hide behind LDS-fed compute. t-reduction via shfl_xor(16/32)
// within the wave (no big LDS scratch), then 16-wave LDS reduce.
#define TRP 132
__global__ __launch_bounds__(1024, 4) void k_main(
    const _Float16* __restrict__ AT, const float* __restrict__ G,
    const float* __restrict__ bvec, const float* __restrict__ D1,
    const float* __restrict__ D2, float* __restrict__ out) {
  __shared__ __align__(16) _Float16 AL[512 * MM];   // cols 512..1023, 131 KB
  __shared__ float td_sh[NN];
  __shared__ float di_sh[NN];
  __shared__ float b_sh[MM];
  __shared__ float s_sh[MM];
  __shared__ __align__(16) _Float16 u_h[MM];
  __shared__ __align__(16) float t_redW[16][TRP];   // 8.4 KB

  int b = blockIdx.x;
  int tid = threadIdx.x;
  const _Float16* ATb = AT + (size_t)b * NN * MM;
  const float* Gb = G + (size_t)b * MM * MM;

  // ---- prologue: G into registers, 8 threads per row, 16 elems each
  int sub = tid & 7, r = tid >> 3;
  float g[16];
#pragma unroll
  for (int s = 0; s < 4; ++s) {
    float4 v = *(const float4*)&Gb[(size_t)r * MM + 16 * sub + 4 * s];
    g[4 * s + 0] = v.x; g[4 * s + 1] = v.y;
    g[4 * s + 2] = v.z; g[4 * s + 3] = v.w;
  }
  {
    float d1 = D1[(size_t)b * NN + tid];
    float d2 = D2[(size_t)b * NN + tid];
    td_sh[tid] = ALPHA * fabsf(d1);
    di_sh[tid] = 1.0f / (1.0f + 2.0f * ALPHA * d2 * d2);
  }
  if (tid < MM) {
    float bb = bvec[(size_t)b * MM + tid];
    b_sh[tid] = bb;
    s_sh[tid] = -bb;   // s_0 = A*y_0 - b = -b
  }
  // ---- load LDS half of A (cols 512..1023)
  {
    const uint4* src = (const uint4*)(ATb + (size_t)512 * MM);
    uint4* dst = (uint4*)AL;
#pragma unroll
    for (int i = 0; i < 8; ++i) dst[tid + 1024 * i] = src[tid + 1024 * i];
  }
  __syncthreads();

  int l16 = tid & 15;          // lane in 16-group
  int grp4 = (tid >> 4) & 3;   // group within wave
  int w = tid >> 6;            // wave 0..15
  int mbase = 8 * l16;
  int nG = 32 * w;             // global col base  (cols 0..511)
  int nL = 32 * w;             // LDS col base     (cols 512..1023 -> AL idx)
  float zreg[16];
#pragma unroll
  for (int s = 0; s < 16; ++s) zreg[s] = 0.0f;

  for (int it = 0; it < ITERS; ++it) {
    bool last = (it == ITERS - 1);
    // ---- u = G * s  (8 threads per row)
    {
      float up = 0.0f;
      int j0 = 16 * sub;
#pragma unroll
      for (int jj = 0; jj < 16; ++jj) up += g[jj] * s_sh[j0 + jj];
      up += __shfl_xor(up, 1);
      up += __shfl_xor(up, 2);
      up += __shfl_xor(up, 4);
      if (sub == 0) u_h[r] = (_Float16)up;
    }
    __syncthreads();
    HU uu;
    uu.f = *(const float4*)&u_h[mbase];
    float t[8];
#pragma unroll
    for (int k = 0; k < 8; ++k) t[k] = 0.0f;

#pragma unroll
    for (int s = 0; s < 16; ++s) {
      // steps 0..7: global cols nG+4s+grp4 (issue early); 8..15: LDS cols
      int nloc = 4 * (s & 7) + grp4;
      int n = (s < 8) ? (nG + nloc) : (512 + nL + nloc);
      HU av;
      if (s < 8)
        av.f = *(const float4*)&ATb[(size_t)(nG + nloc) * MM + mbase];
      else
        av.f = *(const float4*)&AL[(nL + nloc) * MM + mbase];
      float cp = 0.0f;
      cp = __builtin_amdgcn_fdot2(av.h[0], uu.h[0], cp, false);
      cp = __builtin_amdgcn_fdot2(av.h[1], uu.h[1], cp, false);
      cp = __builtin_amdgcn_fdot2(av.h[2], uu.h[2], cp, false);
      cp = __builtin_amdgcn_fdot2(av.h[3], uu.h[3], cp, false);
      cp += __shfl_xor(cp, 1);
      cp += __shfl_xor(cp, 2);
      cp += __shfl_xor(cp, 4);
      cp += __shfl_xor(cp, 8);   // all 16 lanes hold corr[n]
      float zn = zreg[s];
      float td = td_sh[n];
      float di = di_sh[n];
      float xm = zn - td, xp = zn + td;
      float xh = xm > 0.0f ? xm * di : (xp < 0.0f ? xp * di : 0.0f);
      if (!last) {
        float z1 = xh - cp;                     // z_{i+1}
        float xm1 = z1 - td, xp1 = z1 + td;
        float xh1 = xm1 > 0.0f ? xm1 * di : (xp1 < 0.0f ? xp1 * di : 0.0f);
        float y = 2.0f * xh1 - z1;              // y_{i+1}
        zreg[s] = z1;
        t[0] += (float)av.h[0].x * y; t[1] += (float)av.h[0].y * y;
        t[2] += (float)av.h[1].x * y; t[3] += (float)av.h[1].y * y;
        t[4] += (float)av.h[2].x * y; t[5] += (float)av.h[2].y * y;
        t[6] += (float)av.h[3].x * y; t[7] += (float)av.h[3].y * y;
      } else {
        float y = 2.0f * xh - zn;               // y_99 from z_99
        zreg[s] = y - cp;                       // x_99 (output)
      }
    }

    if (!last) {
      // ---- in-wave cross-group reduce: groups at lanes {l16,+16,+32,+48}
#pragma unroll
      for (int k = 0; k < 8; ++k) {
        t[k] += __shfl_xor(t[k], 16);
        t[k] += __shfl_xor(t[k], 32);
      }
      if (grp4 == 0) {
        float4 ta; ta.x = t[0]; ta.y = t[1]; ta.z = t[2]; ta.w = t[3];
        float4 tb; tb.x = t[4]; tb.y = t[5]; tb.z = t[6]; tb.w = t[7];
        *(float4*)&t_redW[w][mbase] = ta;
        *(float4*)&t_redW[w][mbase + 4] = tb;
      }
      __syncthreads();
      if (tid < MM) {
        float ssum = -b_sh[tid];
#pragma unroll
        for (int h = 0; h < 16; ++h) ssum += t_redW[h][tid];
        s_sh[tid] = ssum;        // s = A*y - b for next pass's u
      }
      __syncthreads();
    }
  }

  if (l16 == 0) {
    float* outb = out + (size_t)b * NN;
#pragma unroll
    for (int s = 0; s < 16; ++s) {
      int nloc = 4 * (s & 7) + grp4;
      int n = (s < 8) ? (nG + nloc) : (512 + nL + nloc);
      outb[n] = zreg[s];
    }
  }
}

// ---------------------------------------------------------------------------
extern "C" void kernel_launch(void* const* d_in, const int* in_sizes, int n_in,
                              void* d_out, int out_size, void* d_ws, size_t ws_size,
                              hipStream_t stream) {
  const float* A  = (const float*)d_in[0];  // (BS, M, N)
  const float* bv = (const float*)d_in[1];  // (BS, M)
  const float* D1 = (const float*)d_in[2];  // (BS, N)
  const float* D2 = (const float*)d_in[3];  // (BS, N)
  float* out = (float*)d_out;               // (BS, N)

  _Float16* ATh = (_Float16*)d_ws;                              // 67 MB
  float* G = (float*)((char*)d_ws + (size_t)BS * NN * MM * 2);  // 16.7 MB

  k_aat<<<BS, 512, 0, stream>>>(A, G, ATh);
  k_inv<<<BS, 256, 0, stream>>>(G);
  k_main<<<BS, 1024, 0, stream>>>(ATh, G, bv, D1, D2, out);
}